// Round 7
// baseline (227.360 us; speedup 1.0000x reference)
//
#include <hip/hip_runtime.h>
#include <cstdint>
#include <cstddef>

// DigitCapsules routing: B=256, R=1152, C=10, IC=8, OC=16, 3 iters.
// R7 (7 launches):
//   caps_u:  u[b][c][r][o] bf16 (94 MB). R6's proven shape (VGPR=64, no spill).
//   caps_s1: s1 = 0.1*sum_r u computed DIRECTLY from x,W as a split-K GEMM
//            (pass 1 never touches u!). 144 r-chunk partials -> s1_reduce.
//   2x { caps_pass: 4608 blocks (256 b x 18 r-splits of 64), one r/thread,
//        no sweep loop (latency fix); reduce18: squash + vsum/out. }
// Logits linear in v: b_t = u.(v1+..+v_{t-1}) -> running vsum, 1 pass/iter.
// REGISTER DISCIPLINE: all kernels use shapes proven <=96 VGPR, no spills.
#define NB 256
#define NR 1152
#define NC 10
#define NI 8
#define NO 16
#define NSPLIT 18
#define RSPL 64      // r per split = one 64-lane rl sweep
#define NRC 144      // r-chunks for caps_u / caps_s1 (8 r each)

static __device__ __forceinline__ uint32_t bf16_pack2(float lo, float hi) {
    uint32_t vl = __float_as_uint(lo);
    vl = vl + 0x7FFFu + ((vl >> 16) & 1u);
    uint32_t vh = __float_as_uint(hi);
    vh = vh + 0x7FFFu + ((vh >> 16) & 1u);
    return (vl >> 16) | (vh & 0xFFFF0000u);
}

// -------------------------------------------------------------------------
// caps_u: grid 2304 = 144 r-chunks(8 r) x 16 b-groups(16 b). 320 thr:
// t = c*32 + rl*4 + oq. W[r][c][i][oq*4..+3] = 8 float4 in regs. UNCHANGED R6.
__global__ __launch_bounds__(320, 2) void caps_u_kernel(
    const float* __restrict__ x, const float* __restrict__ W,
    uint32_t* __restrict__ u)
{
    const int t  = threadIdx.x;
    const int c  = t >> 5;             // 0..9
    const int rl = (t & 31) >> 2;      // 0..7
    const int oq = t & 3;              // 0..3
    const int rc = blockIdx.x >> 4;    // 0..143
    const int bg = blockIdx.x & 15;    // 0..15
    const int b0 = bg * 16;
    const int r  = rc * 8 + rl;

    __shared__ float xs[16][8][8];     // 4 KB

    if (t < 256) {                     // 256 float4 = x[b0..+16)[rc*8..+8)[8]
        const int bi = t >> 4, rem = t & 15;
        const int rr = rem >> 1, hf = rem & 1;
        *(float4*)&xs[bi][rr][hf * 4] =
            *(const float4*)(x + ((size_t)(b0 + bi) * NR + rc * 8 + rr) * 8 + hf * 4);
    }

    const float* wb = W + ((size_t)r * NC + c) * (NI * NO) + oq * 4;
    float4 wf[8];
#pragma unroll
    for (int i = 0; i < 8; ++i) wf[i] = *(const float4*)(wb + i * NO);

    __syncthreads();

    for (int bi = 0; bi < 16; ++bi) {
        float xr[8];
#pragma unroll
        for (int i = 0; i < 8; ++i) xr[i] = xs[bi][rl][i];
        float ax = 0.f, ay = 0.f, az = 0.f, aw = 0.f;
#pragma unroll
        for (int i = 0; i < 8; ++i) {
            const float xv = xr[i];
            ax = fmaf(xv, wf[i].x, ax); ay = fmaf(xv, wf[i].y, ay);
            az = fmaf(xv, wf[i].z, az); aw = fmaf(xv, wf[i].w, aw);
        }
        uint2 s;
        s.x = bf16_pack2(ax, ay);
        s.y = bf16_pack2(az, aw);
        *(uint2*)(u + (((size_t)(b0 + bi) * NC + c) * NR + r) * 8 + oq * 2) = s;
    }
}

// -------------------------------------------------------------------------
// caps_s1: S[b,c,o] partials = sum over this block's 8 r of x.W (fp32).
// Same grid/shape as caps_u; per b: 3-level xor-shuffle reduces rl(8),
// rl==0 lanes store float4 partial to part1[rc][b][c*16+oq*4].
__global__ __launch_bounds__(320, 2) void caps_s1_kernel(
    const float* __restrict__ x, const float* __restrict__ W,
    float* __restrict__ part1)
{
    const int t  = threadIdx.x;
    const int c  = t >> 5;
    const int rl = (t & 31) >> 2;
    const int oq = t & 3;
    const int rc = blockIdx.x >> 4;
    const int bg = blockIdx.x & 15;
    const int b0 = bg * 16;
    const int r  = rc * 8 + rl;

    __shared__ float xs[16][8][8];

    if (t < 256) {
        const int bi = t >> 4, rem = t & 15;
        const int rr = rem >> 1, hf = rem & 1;
        *(float4*)&xs[bi][rr][hf * 4] =
            *(const float4*)(x + ((size_t)(b0 + bi) * NR + rc * 8 + rr) * 8 + hf * 4);
    }

    const float* wb = W + ((size_t)r * NC + c) * (NI * NO) + oq * 4;
    float4 wf[8];
#pragma unroll
    for (int i = 0; i < 8; ++i) wf[i] = *(const float4*)(wb + i * NO);

    __syncthreads();

    for (int bi = 0; bi < 16; ++bi) {
        float xr[8];
#pragma unroll
        for (int i = 0; i < 8; ++i) xr[i] = xs[bi][rl][i];
        float a[4] = {0.f, 0.f, 0.f, 0.f};
#pragma unroll
        for (int i = 0; i < 8; ++i) {
            const float xv = xr[i];
            a[0] = fmaf(xv, wf[i].x, a[0]); a[1] = fmaf(xv, wf[i].y, a[1]);
            a[2] = fmaf(xv, wf[i].z, a[2]); a[3] = fmaf(xv, wf[i].w, a[3]);
        }
        // reduce over rl (lane bits 2..4): xor 4, 8, 16
#pragma unroll
        for (int off = 4; off <= 16; off <<= 1)
#pragma unroll
            for (int j = 0; j < 4; ++j) a[j] += __shfl_xor(a[j], off);
        if ((t & 28) == 0) {   // rl == 0 lanes
            *(float4*)(part1 + ((size_t)rc * NB + b0 + bi) * 160 + c * 16 + oq * 4)
                = *(float4*)a;
        }
    }
}

// s1_reduce: vsum = squash(0.1 * sum of 144 partials). grid 256, 192 thr.
__global__ __launch_bounds__(192) void caps_s1_reduce_kernel(
    const float* __restrict__ part1, float* __restrict__ vsum)
{
    const int b = blockIdx.x;
    const int t = threadIdx.x;
    if (t >= 160) return;
    float s0 = 0.f, s1 = 0.f, s2 = 0.f, s3 = 0.f;
    const float* p = part1 + (size_t)b * 160 + t;
#pragma unroll 4
    for (int g = 0; g < NRC; g += 4) {
        s0 += p[(size_t)(g + 0) * NB * 160];
        s1 += p[(size_t)(g + 1) * NB * 160];
        s2 += p[(size_t)(g + 2) * NB * 160];
        s3 += p[(size_t)(g + 3) * NB * 160];
    }
    const float s = 0.1f * ((s0 + s1) + (s2 + s3));
    float n2 = s * s;
    n2 += __shfl_xor(n2, 1);
    n2 += __shfl_xor(n2, 2);
    n2 += __shfl_xor(n2, 4);
    n2 += __shfl_xor(n2, 8);
    const float nrm   = sqrtf(n2);
    const float scale = n2 / (1.f + n2) / (nrm + 1e-8f);
    vsum[(size_t)b * 160 + t] = scale * s;
}

// -------------------------------------------------------------------------
// Routing pass (iters 2,3): block = (b, sp), 256 thr = 64 rl x 4 oq, ONE r
// per thread (no sweep loop). cc = softmax_c(u.vsum); partial s -> part2.
__global__ __launch_bounds__(256, 2) void caps_pass_kernel(
    const uint32_t* __restrict__ u, const float* __restrict__ vsum,
    float* __restrict__ part2)
{
    const int b  = blockIdx.x / NSPLIT;
    const int sp = blockIdx.x % NSPLIT;
    const int t  = threadIdx.x;
    const int oq = t & 3;
    const int rl = t >> 2;    // 0..63
    const int r  = sp * RSPL + rl;

    __shared__ float vss[160];
    __shared__ float sred[4][160];

    if (t < 160) vss[t] = vsum[(size_t)b * 160 + t];
    __syncthreads();

    const uint2* ub = (const uint2*)u + (size_t)b * NC * NR * 4 + oq;
    uint2 q[10];
#pragma unroll
    for (int c = 0; c < 10; ++c) q[c] = ub[((size_t)c * NR + r) * 4];

    float lg[10];
#pragma unroll
    for (int c = 0; c < 10; ++c) {
        const float4 vq = *(const float4*)&vss[c * 16 + oq * 4];
        float d = __uint_as_float(q[c].x << 16) * vq.x;
        d = fmaf(__uint_as_float(q[c].x & 0xFFFF0000u), vq.y, d);
        d = fmaf(__uint_as_float(q[c].y << 16),         vq.z, d);
        d = fmaf(__uint_as_float(q[c].y & 0xFFFF0000u), vq.w, d);
        lg[c] = d;
    }
#pragma unroll
    for (int c = 0; c < 10; ++c) {        // finish o-dot over 4 oq lanes
        lg[c] += __shfl_xor(lg[c], 1);
        lg[c] += __shfl_xor(lg[c], 2);
    }
    float m = lg[0];
#pragma unroll
    for (int c = 1; c < 10; ++c) m = fmaxf(m, lg[c]);
    float wgt[10], ssum = 0.f;
#pragma unroll
    for (int c = 0; c < 10; ++c) { wgt[c] = __expf(lg[c] - m); ssum += wgt[c]; }
    const float inv = 1.f / ssum;

    float acc[10][4];
#pragma unroll
    for (int c = 0; c < 10; ++c) {
        const float wv = wgt[c] * inv;
        acc[c][0] = wv * __uint_as_float(q[c].x << 16);
        acc[c][1] = wv * __uint_as_float(q[c].x & 0xFFFF0000u);
        acc[c][2] = wv * __uint_as_float(q[c].y << 16);
        acc[c][3] = wv * __uint_as_float(q[c].y & 0xFFFF0000u);
    }

    // in-wave reduce over 16 rl-lanes (tid bits 2..5)
#pragma unroll
    for (int off = 4; off <= 32; off <<= 1)
#pragma unroll
        for (int c = 0; c < 10; ++c)
#pragma unroll
            for (int j = 0; j < 4; ++j) acc[c][j] += __shfl_xor(acc[c][j], off);

    const int wv = t >> 6;
    if ((t & 63) < 4) {
#pragma unroll
        for (int c = 0; c < 10; ++c)
#pragma unroll
            for (int j = 0; j < 4; ++j)
                sred[wv][c * 16 + oq * 4 + j] = acc[c][j];
    }
    __syncthreads();

    if (t < 160) {
        part2[((size_t)sp * NB + b) * 160 + t]
            = sred[0][t] + sred[1][t] + sred[2][t] + sred[3][t];
    }
}

// reduce18 + squash. mode 1: vsum += v ; mode 2: out = v
__global__ __launch_bounds__(192) void caps_reduce_kernel(
    const float* __restrict__ part2, float* __restrict__ vsum,
    float* __restrict__ out, const int mode)
{
    const int b = blockIdx.x;
    const int t = threadIdx.x;
    if (t >= 160) return;
    float s = 0.f;
#pragma unroll
    for (int sp = 0; sp < NSPLIT; ++sp)
        s += part2[((size_t)sp * NB + b) * 160 + t];
    float n2 = s * s;
    n2 += __shfl_xor(n2, 1);
    n2 += __shfl_xor(n2, 2);
    n2 += __shfl_xor(n2, 4);
    n2 += __shfl_xor(n2, 8);
    const float nrm   = sqrtf(n2);
    const float scale = n2 / (1.f + n2) / (nrm + 1e-8f);
    const float v = scale * s;
    if (mode == 1) vsum[(size_t)b * 160 + t] += v;
    else           out[(size_t)b * 160 + t] = v;
}

// -------------------------------------------------------------------------
extern "C" void kernel_launch(void* const* d_in, const int* in_sizes, int n_in,
                              void* d_out, int out_size, void* d_ws, size_t ws_size,
                              hipStream_t stream) {
    const float* x = (const float*)d_in[0];   // [256,1152,8]
    const float* W = (const float*)d_in[1];   // [1,1152,10,8,16]
    float* out = (float*)d_out;               // [256,10,16]

    // ws: u bf16 94,371,840 | part1 144*256*160*4 = 23,592,960
    //     part2 18*256*160*4 = 2,949,120 | vsum 163,840
    uint8_t*  ws   = (uint8_t*)d_ws;
    uint32_t* u    = (uint32_t*)ws;
    float*    prt1 = (float*)(ws + 94371840u);
    float*    prt2 = (float*)(ws + 94371840u + 23592960u);
    float*    vsm  = (float*)(ws + 94371840u + 23592960u + 2949120u);

    caps_u_kernel        <<<2304, 320, 0, stream>>>(x, W, u);
    caps_s1_kernel       <<<2304, 320, 0, stream>>>(x, W, prt1);
    caps_s1_reduce_kernel<<<NB, 192, 0, stream>>>(prt1, vsm);
    caps_pass_kernel     <<<NB * NSPLIT, 256, 0, stream>>>(u, vsm, prt2);
    caps_reduce_kernel   <<<NB, 192, 0, stream>>>(prt2, vsm, nullptr, 1);
    caps_pass_kernel     <<<NB * NSPLIT, 256, 0, stream>>>(u, vsm, prt2);
    caps_reduce_kernel   <<<NB, 192, 0, stream>>>(prt2, nullptr, out, 2);
}

// Round 8
// 155.520 us; speedup vs baseline: 1.4619x; 1.4619x over previous
//
#include <hip/hip_runtime.h>
#include <cstdint>
#include <cstddef>

// DigitCapsules routing: B=256, R=1152, C=10, IC=8, OC=16, 3 iters.
// R8 (7 launches) — R6 structure, DS-pipe-optimized passes:
//   caps_u: u[b][c][r][o] bf16 (94 MB). R6's proven shape (64 VGPR, no spill).
//   3x { caps_pass(NSPLIT=2: 512 blocks, 9 sweeps of 64 r per thread):
//          one u-read; mode0 skips logits entirely; the 320-DS-op epilogue
//          shuffle-reduce is paid once per 9 r (R7 paid it per 1 r -> DS-pipe
//          bound at 43 us/CU);
//        caps_reduce: sum 2 partials + squash + vsum/out }
// Logits linear in v: b_t = u.(v1+..+v_{t-1}) -> running vsum, 1 pass/iter.
// DS-pipe model (R7 post-mortem): pass DS/CU = 4n*(720/n+320)*4cyc, n=NSPLIT.
// n=2 -> ~9 us DS, memory ~18-20 us -> pass ~22-26 us.
#define NB 256
#define NR 1152
#define NC 10
#define NI 8
#define NO 16
#define NSPLIT 2
#define NSWEEP 9     // r-sweeps per thread: 9*64 = 576 = NR/NSPLIT

static __device__ __forceinline__ uint32_t bf16_pack2(float lo, float hi) {
    uint32_t vl = __float_as_uint(lo);
    vl = vl + 0x7FFFu + ((vl >> 16) & 1u);
    uint32_t vh = __float_as_uint(hi);
    vh = vh + 0x7FFFu + ((vh >> 16) & 1u);
    return (vl >> 16) | (vh & 0xFFFF0000u);
}

// -------------------------------------------------------------------------
// caps_u: grid 2304 = 144 r-chunks(8 r) x 16 b-groups(16 b). 320 thr:
// t = c*32 + rl*4 + oq. W[r][c][i][oq*4..+3] = 8 float4 in regs.
// R6-proven; no min-waves bound (VGPR 64 -> let occupancy float up).
__global__ __launch_bounds__(320) void caps_u_kernel(
    const float* __restrict__ x, const float* __restrict__ W,
    uint32_t* __restrict__ u)
{
    const int t  = threadIdx.x;
    const int c  = t >> 5;             // 0..9
    const int rl = (t & 31) >> 2;      // 0..7
    const int oq = t & 3;              // 0..3
    const int rc = blockIdx.x >> 4;    // 0..143
    const int bg = blockIdx.x & 15;    // 0..15
    const int b0 = bg * 16;
    const int r  = rc * 8 + rl;

    __shared__ float xs[16][8][8];     // 4 KB; rows 32B-aligned for b128

    if (t < 256) {                     // 256 float4 = x[b0..+16)[rc*8..+8)[8]
        const int bi = t >> 4, rem = t & 15;
        const int rr = rem >> 1, hf = rem & 1;
        *(float4*)&xs[bi][rr][hf * 4] =
            *(const float4*)(x + ((size_t)(b0 + bi) * NR + rc * 8 + rr) * 8 + hf * 4);
    }

    const float* wb = W + ((size_t)r * NC + c) * (NI * NO) + oq * 4;
    float4 wf[8];
#pragma unroll
    for (int i = 0; i < 8; ++i) wf[i] = *(const float4*)(wb + i * NO);

    __syncthreads();

    for (int bi = 0; bi < 16; ++bi) {
        const float4 xv4a = *(const float4*)&xs[bi][rl][0];   // ds_read_b128
        const float4 xv4b = *(const float4*)&xs[bi][rl][4];
        const float xr[8] = {xv4a.x, xv4a.y, xv4a.z, xv4a.w,
                             xv4b.x, xv4b.y, xv4b.z, xv4b.w};
        float ax = 0.f, ay = 0.f, az = 0.f, aw = 0.f;
#pragma unroll
        for (int i = 0; i < 8; ++i) {
            const float xv = xr[i];
            ax = fmaf(xv, wf[i].x, ax); ay = fmaf(xv, wf[i].y, ay);
            az = fmaf(xv, wf[i].z, az); aw = fmaf(xv, wf[i].w, aw);
        }
        uint2 s;
        s.x = bf16_pack2(ax, ay);
        s.y = bf16_pack2(az, aw);
        *(uint2*)(u + (((size_t)(b0 + bi) * NC + c) * NR + r) * 8 + oq * 2) = s;
    }
}

// -------------------------------------------------------------------------
// Routing pass: block = (b, sp), 256 thr = 64 rl x 4 oq, NSWEEP=9 sweeps.
// mode 0: uniform weights (0.1 folded at epilogue), NO logits/softmax.
// mode 1: cc = softmax_c(u.vsum). Partial s -> part2[sp][b][160]. No atomics.
__global__ __launch_bounds__(256, 2) void caps_pass_kernel(
    const uint32_t* __restrict__ u, const float* __restrict__ vsum,
    float* __restrict__ part2, const int mode)
{
    const int b  = blockIdx.x >> 1;
    const int sp = blockIdx.x & 1;
    const int t  = threadIdx.x;
    const int oq = t & 3;
    const int rl = t >> 2;    // 0..63

    __shared__ float vss[160];
    __shared__ float sred[4][160];

    if (mode != 0 && t < 160) vss[t] = vsum[(size_t)b * 160 + t];
    __syncthreads();

    float acc[10][4];
#pragma unroll
    for (int c = 0; c < 10; ++c)
#pragma unroll
        for (int j = 0; j < 4; ++j) acc[c][j] = 0.f;

    const uint2* ub = (const uint2*)u + (size_t)b * NC * NR * 4 + oq;

    for (int k = 0; k < NSWEEP; ++k) {
        const int r = sp * (NSWEEP * 64) + k * 64 + rl;
        uint2 q[10];
#pragma unroll
        for (int c = 0; c < 10; ++c) q[c] = ub[((size_t)c * NR + r) * 4];

        if (mode != 0) {
            float lg[10];
#pragma unroll
            for (int c = 0; c < 10; ++c) {
                const float4 vq = *(const float4*)&vss[c * 16 + oq * 4];
                float d = __uint_as_float(q[c].x << 16) * vq.x;
                d = fmaf(__uint_as_float(q[c].x & 0xFFFF0000u), vq.y, d);
                d = fmaf(__uint_as_float(q[c].y << 16),         vq.z, d);
                d = fmaf(__uint_as_float(q[c].y & 0xFFFF0000u), vq.w, d);
                lg[c] = d;
            }
#pragma unroll
            for (int c = 0; c < 10; ++c) {    // finish o-dot over 4 oq lanes
                lg[c] += __shfl_xor(lg[c], 1);
                lg[c] += __shfl_xor(lg[c], 2);
            }
            float m = lg[0];
#pragma unroll
            for (int c = 1; c < 10; ++c) m = fmaxf(m, lg[c]);
            float wgt[10], ssum = 0.f;
#pragma unroll
            for (int c = 0; c < 10; ++c) { wgt[c] = __expf(lg[c] - m); ssum += wgt[c]; }
            const float inv = 1.f / ssum;
#pragma unroll
            for (int c = 0; c < 10; ++c) {
                const float wv = wgt[c] * inv;
                acc[c][0] = fmaf(wv, __uint_as_float(q[c].x << 16),         acc[c][0]);
                acc[c][1] = fmaf(wv, __uint_as_float(q[c].x & 0xFFFF0000u), acc[c][1]);
                acc[c][2] = fmaf(wv, __uint_as_float(q[c].y << 16),         acc[c][2]);
                acc[c][3] = fmaf(wv, __uint_as_float(q[c].y & 0xFFFF0000u), acc[c][3]);
            }
        } else {
#pragma unroll
            for (int c = 0; c < 10; ++c) {
                acc[c][0] += __uint_as_float(q[c].x << 16);
                acc[c][1] += __uint_as_float(q[c].x & 0xFFFF0000u);
                acc[c][2] += __uint_as_float(q[c].y << 16);
                acc[c][3] += __uint_as_float(q[c].y & 0xFFFF0000u);
            }
        }
    }

    // in-wave reduce over 16 rl-lanes (tid bits 2..5) — paid once per 9 r
#pragma unroll
    for (int off = 4; off <= 32; off <<= 1)
#pragma unroll
        for (int c = 0; c < 10; ++c)
#pragma unroll
            for (int j = 0; j < 4; ++j) acc[c][j] += __shfl_xor(acc[c][j], off);

    const int wv = t >> 6;
    if ((t & 63) < 4) {
#pragma unroll
        for (int c = 0; c < 10; ++c)
#pragma unroll
            for (int j = 0; j < 4; ++j)
                sred[wv][c * 16 + oq * 4 + j] = acc[c][j];
    }
    __syncthreads();

    if (t < 160) {
        float s = sred[0][t] + sred[1][t] + sred[2][t] + sred[3][t];
        if (mode == 0) s *= 0.1f;
        part2[((size_t)sp * NB + b) * 160 + t] = s;
    }
}

// -------------------------------------------------------------------------
// sum NSPLIT partials + squash. grid=256 (b), 192 thr (160 active).
// mode 0: vsum = v ; 1: vsum += v ; 2: out = v
__global__ __launch_bounds__(192) void caps_reduce_kernel(
    const float* __restrict__ part2, float* __restrict__ vsum,
    float* __restrict__ out, const int mode)
{
    const int b = blockIdx.x;
    const int t = threadIdx.x;
    if (t >= 160) return;
    float s = 0.f;
#pragma unroll
    for (int sp = 0; sp < NSPLIT; ++sp)
        s += part2[((size_t)sp * NB + b) * 160 + t];
    float n2 = s * s;                 // squash over o (t & 15)
    n2 += __shfl_xor(n2, 1);
    n2 += __shfl_xor(n2, 2);
    n2 += __shfl_xor(n2, 4);
    n2 += __shfl_xor(n2, 8);
    const float nrm   = sqrtf(n2);
    const float scale = n2 / (1.f + n2) / (nrm + 1e-8f);
    const float v = scale * s;
    if (mode == 0)      vsum[(size_t)b * 160 + t] = v;
    else if (mode == 1) vsum[(size_t)b * 160 + t] += v;
    else                out[(size_t)b * 160 + t] = v;
}

// -------------------------------------------------------------------------
extern "C" void kernel_launch(void* const* d_in, const int* in_sizes, int n_in,
                              void* d_out, int out_size, void* d_ws, size_t ws_size,
                              hipStream_t stream) {
    const float* x = (const float*)d_in[0];   // [256,1152,8]
    const float* W = (const float*)d_in[1];   // [1,1152,10,8,16]
    float* out = (float*)d_out;               // [256,10,16]

    // ws: u bf16 94,371,840 | part2 2*256*160*4 = 327,680 | vsum 163,840
    uint8_t*  ws  = (uint8_t*)d_ws;
    uint32_t* u   = (uint32_t*)ws;
    float*    prt = (float*)(ws + 94371840u);
    float*    vsm = (float*)(ws + 94371840u + 327680u);

    caps_u_kernel     <<<2304, 320, 0, stream>>>(x, W, u);
    caps_pass_kernel  <<<NB * NSPLIT, 256, 0, stream>>>(u, vsm, prt, 0);
    caps_reduce_kernel<<<NB, 192, 0, stream>>>(prt, vsm, nullptr, 0);
    caps_pass_kernel  <<<NB * NSPLIT, 256, 0, stream>>>(u, vsm, prt, 1);
    caps_reduce_kernel<<<NB, 192, 0, stream>>>(prt, vsm, nullptr, 1);
    caps_pass_kernel  <<<NB * NSPLIT, 256, 0, stream>>>(u, vsm, prt, 1);
    caps_reduce_kernel<<<NB, 192, 0, stream>>>(prt, nullptr, out, 2);
}